// Round 1
// baseline (450.855 us; speedup 1.0000x reference)
//
#include <hip/hip_runtime.h>
#include <stdint.h>

// SageLayer: N=8192, F=1024, O=1024, K=2F=2048, NUM_NEIGH=10. Inputs f32.
//
// ROUND EXPERIMENT: zero-workspace build. Theory: the two 1-GiB
// fillBufferAligned dispatches (2 x 160.2 us = 320.5 us) in the timed graph
// are d_ws poison/restore; 390.5 - 320.5 = 70.0 us == roofline sum of our 4
// kernels. All scratch is folded into Out (32 MB):
//   Agg bf16 [8192][1024] -> Out bytes [0, 16M)
//   Wtb bf16 [1024][2048] -> Out bytes [16M, 20M)
//   A-left (bf16(X)) is never materialized: GEMM converts X on the fly.
// In-place hazard (epilogue overwrites scratch) is handled by a two-phase
// grid spin barrier; counters live in the two Out cells owned by block 5,
// which defers those two stores past barrier 2.
#define NN 8192
#define FD 1024
#define OD 1024
#define KD 2048
#define NB 10
#define NBLK 512  // gemm grid; all co-resident (2/CU x 256 CU via launch_bounds)

typedef short bf16x8 __attribute__((ext_vector_type(8)));
typedef float f32x4  __attribute__((ext_vector_type(4)));

static __device__ __forceinline__ float bf2f(ushort u) {
  union { uint32_t i; float f; } v; v.i = ((uint32_t)u) << 16; return v.f;
}
static __device__ __forceinline__ ushort f2bf(float f) {
  union { float f; uint32_t i; } v; v.f = f;
  uint32_t x = v.i;
  return (ushort)((x + 0x7FFFu + ((x >> 16) & 1u)) >> 16);  // RNE
}
static __device__ __forceinline__ bf16x8 cvt8(const float* p) {
  const float4 a = *reinterpret_cast<const float4*>(p);
  const float4 b = *reinterpret_cast<const float4*>(p + 4);
  bf16x8 v;
  v[0] = (short)f2bf(a.x); v[1] = (short)f2bf(a.y);
  v[2] = (short)f2bf(a.z); v[3] = (short)f2bf(a.w);
  v[4] = (short)f2bf(b.x); v[5] = (short)f2bf(b.y);
  v[6] = (short)f2bf(b.z); v[7] = (short)f2bf(b.w);
  return v;
}

// async global->LDS, 16 B/lane. LDS dest must be wave-uniform base + lane*16.
static __device__ __forceinline__ void async16(const ushort* g, ushort* l) {
  __builtin_amdgcn_global_load_lds(
      (const __attribute__((address_space(1))) uint32_t*)(const void*)g,
      (__attribute__((address_space(3))) uint32_t*)(void*)l, 16, 0, 0);
}

// Barrier counters: the two Out cells (5120,0) and (5121,0) — owned by gemm
// block id=5 (panel 40, n-block 0), which defers exactly those two stores.
static __device__ __forceinline__ int* ctr1_of(float* Out) {
  return (int*)(Out + (size_t)5120 * OD);
}
static __device__ __forceinline__ int* ctr2_of(float* Out) {
  return (int*)(Out + (size_t)5121 * OD);
}

// ---------------------------------------------------------------------------
// wprep: Wtb[n][k] = bf16(W[k][n]) into Out[16M,20M). 64x64 LDS-tiled
// transpose + convert. Also zeroes the two barrier counters.
// ---------------------------------------------------------------------------
__global__ __launch_bounds__(1024) void wprep(const float* __restrict__ W,
                                              float* __restrict__ Out) {
  __shared__ float tile[64][65];
  ushort* Wtb = (ushort*)Out + (size_t)NN * FD;  // byte offset 16 MB
  if (blockIdx.x == 0 && blockIdx.y == 0 && threadIdx.x == 0 && threadIdx.y == 0) {
    __hip_atomic_store(ctr1_of(Out), 0, __ATOMIC_RELAXED, __HIP_MEMORY_SCOPE_AGENT);
    __hip_atomic_store(ctr2_of(Out), 0, __ATOMIC_RELAXED, __HIP_MEMORY_SCOPE_AGENT);
  }
  const int k0 = blockIdx.x * 64;
  const int n0 = blockIdx.y * 64;
  const int tx = threadIdx.x;
  const int ty = threadIdx.y;
#pragma unroll
  for (int r = 0; r < 4; ++r) {
    const int kl = ty + r * 16;
    tile[kl][tx] = W[(size_t)(k0 + kl) * OD + n0 + tx];
  }
  __syncthreads();
#pragma unroll
  for (int r = 0; r < 4; ++r) {
    const int nl = ty + r * 16;
    Wtb[(size_t)(n0 + nl) * KD + k0 + tx] = f2bf(tile[tx][nl]);
  }
}

// ---------------------------------------------------------------------------
// aggf: Agg[i][:] = bf16(mean_j X[idx[i][j]][:]) into Out[0,16M).
// Gathers f32 rows of X directly (2 rows per 256-thread block).
// ---------------------------------------------------------------------------
__global__ __launch_bounds__(256) void aggf(const float* __restrict__ X,
                                            const int* __restrict__ idx,
                                            float* __restrict__ Out) {
  ushort* Agg = (ushort*)Out;
  const int row = blockIdx.x * 2 + (threadIdx.x >> 7);
  const int col = (threadIdx.x & 127) * 8;
  const int* ip = idx + (size_t)row * NB;
  int nb[NB];
#pragma unroll
  for (int j = 0; j < NB; ++j) nb[j] = ip[j];
  float acc[8] = {0.f, 0.f, 0.f, 0.f, 0.f, 0.f, 0.f, 0.f};
#pragma unroll
  for (int j = 0; j < NB; ++j) {
    const float* p = X + (size_t)nb[j] * FD + col;
    const float4 a = *reinterpret_cast<const float4*>(p);
    const float4 b = *reinterpret_cast<const float4*>(p + 4);
    acc[0] += a.x; acc[1] += a.y; acc[2] += a.z; acc[3] += a.w;
    acc[4] += b.x; acc[5] += b.y; acc[6] += b.z; acc[7] += b.w;
  }
  bf16x8 o;
#pragma unroll
  for (int e = 0; e < 8; ++e) o[e] = (short)f2bf(acc[e] * 0.1f);
  *reinterpret_cast<bf16x8*>(Agg + (size_t)row * FD + col) = o;
}

// ---------------------------------------------------------------------------
// gemm_nws: Out = [bf16(X) | Agg] @ Wtb^T + b, fully in-place over Out.
// 128x128 tile, BK=64, chunk-rotation LDS swizzle (as gemm_fast3).
// K-half 1 (k<1024): A staged on the fly from X f32 (cvt8 + ds_write_b128
// into the same swizzled slots). K-half 2: A via global_load_lds from Agg.
// After the k-loop: two-phase grid spin barrier, then epilogue (block 5
// defers the two counter cells until barrier 2 completes).
// ---------------------------------------------------------------------------
__global__ __launch_bounds__(256, 2) void gemm_nws(const float* __restrict__ X,
                                                   const float* __restrict__ Bias,
                                                   float* __restrict__ Out) {
  __shared__ ushort lA[128 * 64];  // 16 KB, swizzled [row][chunk]
  __shared__ ushort lB[128 * 64];  // 16 KB
  const ushort* Agg = (const ushort*)Out;
  const ushort* Wtb = (const ushort*)Out + (size_t)NN * FD;
  int* ctr1 = ctr1_of(Out);
  int* ctr2 = ctr2_of(Out);

  const int t  = threadIdx.x;
  // XCD-aware decode: id%8 ~ XCD; XCD c -> m-blocks [8c,8c+8), all 8 n-blocks
  const int id  = blockIdx.x;          // 0..511
  const int xcd = id & 7;
  const int j   = id >> 3;             // 0..63
  const int m0  = (xcd * 8 + (j >> 3)) * 128;
  const int n0  = (j & 7) * 128;

  const int wave = t >> 6;
  const int lane = t & 63;
  const int wm   = (wave & 1) * 64;
  const int wn   = (wave >> 1) * 64;
  const int l15  = lane & 15;
  const int quad = lane >> 4;

  f32x4 acc[4][4];
#pragma unroll
  for (int i = 0; i < 4; ++i)
#pragma unroll
    for (int jj = 0; jj < 4; ++jj) acc[i][jj] = (f32x4){0.f, 0.f, 0.f, 0.f};

  // staging coords: 4 slots per thread per matrix; slot q holds global chunk
  // c = (ch - row) & 7 (so swizzled slot offset == lane-contiguous q*8)
  int rowq[4], cq[4];
  const ushort* gA[4];
  const ushort* gB[4];
#pragma unroll
  for (int i = 0; i < 4; ++i) {
    const int q   = i * 256 + t;       // 0..1023
    const int row = q >> 3;            // 0..127
    const int ch  = q & 7;
    const int c   = (ch - row) & 7;    // source k-chunk (8 elems)
    rowq[i] = row; cq[i] = c;
    gA[i] = Agg + (size_t)(m0 + row) * FD + c * 8;   // agg half (k>=1024)
    gB[i] = Wtb + (size_t)(n0 + row) * KD + c * 8;
  }

  // ---- K-half 1: A from X (on-the-fly convert), B from Wtb ----
  for (int k0 = 0; k0 < FD; k0 += 64) {
#pragma unroll
    for (int i = 0; i < 4; ++i)
      async16(gB[i] + k0, lB + (i * 256 + t) * 8);  // DMA B first: overlaps cvt
#pragma unroll
    for (int i = 0; i < 4; ++i) {
      const bf16x8 v = cvt8(X + (size_t)(m0 + rowq[i]) * FD + k0 + cq[i] * 8);
      *reinterpret_cast<bf16x8*>(lA + (i * 256 + t) * 8) = v;
    }
    __syncthreads();
#pragma unroll
    for (int s = 0; s < 2; ++s) {
      const int c = s * 4 + quad;
      bf16x8 afr[4], bfr[4];
#pragma unroll
      for (int mi = 0; mi < 4; ++mi) {
        const int r = wm + mi * 16 + l15;
        afr[mi] = *reinterpret_cast<const bf16x8*>(lA + r * 64 + ((c + r) & 7) * 8);
      }
#pragma unroll
      for (int ni = 0; ni < 4; ++ni) {
        const int r = wn + ni * 16 + l15;
        bfr[ni] = *reinterpret_cast<const bf16x8*>(lB + r * 64 + ((c + r) & 7) * 8);
      }
#pragma unroll
      for (int mi = 0; mi < 4; ++mi)
#pragma unroll
        for (int ni = 0; ni < 4; ++ni)
          acc[mi][ni] = __builtin_amdgcn_mfma_f32_16x16x32_bf16(afr[mi], bfr[ni], acc[mi][ni], 0, 0, 0);
    }
    __syncthreads();
  }

  // ---- K-half 2: A from Agg (async), B from Wtb cols [1024,2048) ----
  for (int k0 = 0; k0 < FD; k0 += 64) {
#pragma unroll
    for (int i = 0; i < 4; ++i) {
      async16(gA[i] + k0, lA + (i * 256 + t) * 8);
      async16(gB[i] + FD + k0, lB + (i * 256 + t) * 8);
    }
    __syncthreads();
#pragma unroll
    for (int s = 0; s < 2; ++s) {
      const int c = s * 4 + quad;
      bf16x8 afr[4], bfr[4];
#pragma unroll
      for (int mi = 0; mi < 4; ++mi) {
        const int r = wm + mi * 16 + l15;
        afr[mi] = *reinterpret_cast<const bf16x8*>(lA + r * 64 + ((c + r) & 7) * 8);
      }
#pragma unroll
      for (int ni = 0; ni < 4; ++ni) {
        const int r = wn + ni * 16 + l15;
        bfr[ni] = *reinterpret_cast<const bf16x8*>(lB + r * 64 + ((c + r) & 7) * 8);
      }
#pragma unroll
      for (int mi = 0; mi < 4; ++mi)
#pragma unroll
        for (int ni = 0; ni < 4; ++ni)
          acc[mi][ni] = __builtin_amdgcn_mfma_f32_16x16x32_bf16(afr[mi], bfr[ni], acc[mi][ni], 0, 0, 0);
    }
    __syncthreads();
  }

  // ---- grid-wide two-phase barrier (all 512 blocks co-resident) ----
  // Bounded spins: if residency assumption ever breaks we produce garbage
  // (visible FAIL) after ~0.4 s instead of wedging the node.
  if (t == 0) {
    __hip_atomic_fetch_add(ctr1, 1, __ATOMIC_ACQ_REL, __HIP_MEMORY_SCOPE_AGENT);
    for (int it = 0; it < (1 << 21); ++it) {
      if (__hip_atomic_load(ctr1, __ATOMIC_ACQUIRE, __HIP_MEMORY_SCOPE_AGENT) >= NBLK) break;
      __builtin_amdgcn_s_sleep(8);
    }
    __hip_atomic_fetch_add(ctr2, 1, __ATOMIC_ACQ_REL, __HIP_MEMORY_SCOPE_AGENT);
  }
  __syncthreads();

  // ---- epilogue: C/D layout col=lane&15, row=quad*4+reg (verified) ----
  const bool def5 = (id == 5) && (t == 0);  // owns cells (5120,0),(5121,0)
#pragma unroll
  for (int ni = 0; ni < 4; ++ni) {
    const int gn = n0 + wn + ni * 16 + l15;
    const float bv = Bias[gn];
#pragma unroll
    for (int mi = 0; mi < 4; ++mi) {
      const int gm = m0 + wm + mi * 16 + quad * 4;
#pragma unroll
      for (int r = 0; r < 4; ++r) {
        if (def5 && mi == 0 && ni == 0 && r < 2) continue;  // deferred
        Out[(size_t)(gm + r) * OD + gn] = acc[mi][ni][r] + bv;
      }
    }
  }
  if (def5) {
    const float bv0 = Bias[0];
    for (int it = 0; it < (1 << 21); ++it) {
      if (__hip_atomic_load(ctr2, __ATOMIC_ACQUIRE, __HIP_MEMORY_SCOPE_AGENT) >= NBLK) break;
      __builtin_amdgcn_s_sleep(8);
    }
    Out[(size_t)5120 * OD] = acc[0][0][0] + bv0;
    Out[(size_t)5121 * OD] = acc[0][0][1] + bv0;
  }
}

extern "C" void kernel_launch(void* const* d_in, const int* in_sizes, int n_in,
                              void* d_out, int out_size, void* d_ws, size_t ws_size,
                              hipStream_t stream) {
  const float* X   = (const float*)d_in[0];
  // d_in[1] = A: dead code in the reference
  const float* W   = (const float*)d_in[2];
  const float* b   = (const float*)d_in[3];
  const int*   idx = (const int*)d_in[4];
  float* out = (float*)d_out;
  (void)d_ws; (void)ws_size;  // EXPERIMENT: workspace deliberately unused

  wprep<<<dim3(KD / 64, OD / 64), dim3(64, 16), 0, stream>>>(W, out);
  aggf<<<NN / 2, 256, 0, stream>>>(X, idx, out);
  gemm_nws<<<NBLK, 256, 0, stream>>>(X, b, out);
}

// Round 2
// 396.893 us; speedup vs baseline: 1.1360x; 1.1360x over previous
//
#include <hip/hip_runtime.h>
#include <stdint.h>

// SageLayer: N=8192, F=1024, O=1024, K=2F=2048, NUM_NEIGH=10. Inputs f32.
//
// Round 2: revert to the verified ws-based pipeline (fills are unconditional
// harness poison — 2x160us regardless of ws use; round-1 proved it).
// Replace gemm_fast3 (128x128, 2-barrier, drain-to-0, ~800 TF ceiling) with
// gemm_256x128: 256x128 tile, 512 thr / 8 waves (4Mx2N, wave=64x64 — same
// verified fragment code), BK=64, 3-deep LDS pipeline (144 KB), counted
// vmcnt(12) across raw barriers (never drains to 0 in the main loop),
// setprio(1) around the MFMA cluster.
#define NN 8192
#define FD 1024
#define OD 1024
#define KD 2048
#define NB 10

typedef short bf16x8 __attribute__((ext_vector_type(8)));
typedef float f32x4  __attribute__((ext_vector_type(4)));

static __device__ __forceinline__ float bf2f(ushort u) {
  union { uint32_t i; float f; } v; v.i = ((uint32_t)u) << 16; return v.f;
}
static __device__ __forceinline__ ushort f2bf(float f) {
  union { float f; uint32_t i; } v; v.f = f;
  uint32_t x = v.i;
  return (ushort)((x + 0x7FFFu + ((x >> 16) & 1u)) >> 16);  // RNE
}
static __device__ __forceinline__ bf16x8 cvt8(const float* p) {
  const float4 a = *reinterpret_cast<const float4*>(p);
  const float4 b = *reinterpret_cast<const float4*>(p + 4);
  bf16x8 v;
  v[0] = (short)f2bf(a.x); v[1] = (short)f2bf(a.y);
  v[2] = (short)f2bf(a.z); v[3] = (short)f2bf(a.w);
  v[4] = (short)f2bf(b.x); v[5] = (short)f2bf(b.y);
  v[6] = (short)f2bf(b.z); v[7] = (short)f2bf(b.w);
  return v;
}

// async global->LDS, 16 B/lane. LDS dest must be wave-uniform base + lane*16.
static __device__ __forceinline__ void async16(const ushort* g, ushort* l) {
  __builtin_amdgcn_global_load_lds(
      (const __attribute__((address_space(1))) uint32_t*)(const void*)g,
      (__attribute__((address_space(3))) uint32_t*)(void*)l, 16, 0, 0);
}

// ---------------------------------------------------------------------------
// xconv: Ab[i][0:1024] = bf16(X[i][:]).  Ab row stride = KD (2048).
// ---------------------------------------------------------------------------
__global__ __launch_bounds__(256) void xconv(const float* __restrict__ X,
                                             ushort* __restrict__ Ab) {
  const int q   = blockIdx.x * 256 + threadIdx.x;
  const int row = q >> 7;
  const int col = (q & 127) * 8;
  const bf16x8 v = cvt8(X + (size_t)row * FD + col);
  *reinterpret_cast<bf16x8*>(Ab + (size_t)row * KD + col) = v;
}

// ---------------------------------------------------------------------------
// aggk: Ab[i][1024:2048] = bf16(mean_j Xb[idx[i][j]][:]), gathering bf16 rows
// from Ab's left half. 2 rows per 256-thread block.
// ---------------------------------------------------------------------------
__global__ __launch_bounds__(256) void aggk(const int* __restrict__ idx,
                                            ushort* __restrict__ Ab) {
  const int row  = blockIdx.x * 2 + (threadIdx.x >> 7);
  const int lane = threadIdx.x & 127;
  const int col  = lane * 8;
  const int* ip = idx + (size_t)row * NB;
  int nb[NB];
#pragma unroll
  for (int j = 0; j < NB; ++j) nb[j] = ip[j];
  float acc[8] = {0.f, 0.f, 0.f, 0.f, 0.f, 0.f, 0.f, 0.f};
#pragma unroll
  for (int j = 0; j < NB; ++j) {
    const uint4 v = *reinterpret_cast<const uint4*>(Ab + (size_t)nb[j] * KD + col);
    const ushort* u = reinterpret_cast<const ushort*>(&v);
#pragma unroll
    for (int e = 0; e < 8; ++e) acc[e] += bf2f(u[e]);
  }
  bf16x8 o;
#pragma unroll
  for (int e = 0; e < 8; ++e) o[e] = (short)f2bf(acc[e] * 0.1f);
  *reinterpret_cast<bf16x8*>(Ab + (size_t)row * KD + FD + col) = o;
}

// ---------------------------------------------------------------------------
// wconv: Wtb[n][k] = bf16(W[k][n]).  64x64 LDS-tiled transpose + convert.
// ---------------------------------------------------------------------------
__global__ __launch_bounds__(1024) void wconv(const float* __restrict__ W,
                                              ushort* __restrict__ Wtb) {
  __shared__ float tile[64][65];
  const int k0 = blockIdx.x * 64;
  const int n0 = blockIdx.y * 64;
  const int tx = threadIdx.x;
  const int ty = threadIdx.y;
#pragma unroll
  for (int r = 0; r < 4; ++r) {
    const int kl = ty + r * 16;
    tile[kl][tx] = W[(size_t)(k0 + kl) * OD + n0 + tx];
  }
  __syncthreads();
#pragma unroll
  for (int r = 0; r < 4; ++r) {
    const int nl = ty + r * 16;
    Wtb[(size_t)(n0 + nl) * KD + k0 + tx] = f2bf(tile[tx][nl]);
  }
}

// ---------------------------------------------------------------------------
// gemm_256x128: Out = Ab @ Wtb^T + b.
// Tile 256x128, BK=64, 512 threads = 8 waves (4Mx2N, wave tile 64x64).
// 3-deep software pipeline: 3 LDS buffers (A 32KB + B 16KB each -> 144 KB),
// 6 global_load_lds per thread per K-tile. Main loop waits vmcnt(12)
// (2 tiles stay in flight across the barrier — never drains to 0); tail
// peels 12 -> 6 -> 0. Raw s_barrier fused into the waitcnt asm with a
// "memory" clobber so no LDS access can be hoisted across it.
// Chunk-rotation swizzle slot(r,c)=r*64+((c+r)&7)*8 (verified round 0):
// staging stays lane-contiguous (global_load_lds requirement), ds_read_b128
// fragment reads rotate banks 4/row -> conflict-free.
// XCD-aware grid: 256 blocks, xcd owns m-panels [4c,4c+4) (A slice 4 MB = L2).
// ---------------------------------------------------------------------------
__global__ __launch_bounds__(512, 2) void gemm_256x128(const ushort* __restrict__ Ab,
                                                       const ushort* __restrict__ Wtb,
                                                       const float* __restrict__ Bias,
                                                       float* __restrict__ Out) {
  __shared__ ushort lA[3 * 256 * 64];  // 96 KB
  __shared__ ushort lB[3 * 128 * 64];  // 48 KB
  const int t  = threadIdx.x;
  const int id  = blockIdx.x;          // 0..255
  const int xcd = id & 7;
  const int j   = id >> 3;             // 0..31
  const int m0  = (xcd * 4 + (j >> 3)) * 256;
  const int n0  = (j & 7) * 128;

  const int wave = t >> 6;             // 0..7
  const int lane = t & 63;
  const int wm   = (wave >> 1) * 64;   // 0,64,128,192
  const int wn   = (wave & 1) * 64;    // 0,64
  const int l15  = lane & 15;
  const int quad = lane >> 4;

  f32x4 acc[4][4];
#pragma unroll
  for (int i = 0; i < 4; ++i)
#pragma unroll
    for (int jj = 0; jj < 4; ++jj) acc[i][jj] = (f32x4){0.f, 0.f, 0.f, 0.f};

  // staging coords: slot q holds global chunk c=(ch-row)&7 so that the
  // swizzled slot offset equals the lane-contiguous q*8.
  const ushort* gA[4];
  const ushort* gB[2];
#pragma unroll
  for (int i = 0; i < 4; ++i) {
    const int q   = i * 512 + t;       // 0..2047
    const int row = q >> 3;            // 0..255
    const int c   = ((q & 7) - row) & 7;
    gA[i] = Ab + (size_t)(m0 + row) * KD + c * 8;
  }
#pragma unroll
  for (int i = 0; i < 2; ++i) {
    const int q   = i * 512 + t;       // 0..1023
    const int row = q >> 3;            // 0..127
    const int c   = ((q & 7) - row) & 7;
    gB[i] = Wtb + (size_t)(n0 + row) * KD + c * 8;
  }

  auto STAGE = [&](int tile, int buf) {
    const int k0 = tile * 64;
    ushort* la = lA + buf * (256 * 64);
    ushort* lb = lB + buf * (128 * 64);
#pragma unroll
    for (int i = 0; i < 4; ++i) async16(gA[i] + k0, la + (i * 512 + t) * 8);
#pragma unroll
    for (int i = 0; i < 2; ++i) async16(gB[i] + k0, lb + (i * 512 + t) * 8);
  };

  auto COMPUTE = [&](int buf) {
    const ushort* la = lA + buf * (256 * 64);
    const ushort* lb = lB + buf * (128 * 64);
#pragma unroll
    for (int s = 0; s < 2; ++s) {
      const int c = s * 4 + quad;  // k-chunk this lane needs
      bf16x8 afr[4], bfr[4];
#pragma unroll
      for (int mi = 0; mi < 4; ++mi) {
        const int r = wm + mi * 16 + l15;
        afr[mi] = *reinterpret_cast<const bf16x8*>(la + r * 64 + ((c + r) & 7) * 8);
      }
#pragma unroll
      for (int ni = 0; ni < 4; ++ni) {
        const int r = wn + ni * 16 + l15;
        bfr[ni] = *reinterpret_cast<const bf16x8*>(lb + r * 64 + ((c + r) & 7) * 8);
      }
      __builtin_amdgcn_s_setprio(1);
#pragma unroll
      for (int mi = 0; mi < 4; ++mi)
#pragma unroll
        for (int ni = 0; ni < 4; ++ni)
          acc[mi][ni] = __builtin_amdgcn_mfma_f32_16x16x32_bf16(afr[mi], bfr[ni], acc[mi][ni], 0, 0, 0);
      __builtin_amdgcn_s_setprio(0);
    }
  };

  // prologue: fill the 3-deep pipe (18 loads in flight)
  STAGE(0, 0); STAGE(1, 1); STAGE(2, 2);

  int buf = 0;
  // main loop: tiles 0..28, each stages tile+3 (last: 28 -> 31).
  // vmcnt(12): waits own 6 loads of tile t; barrier makes it collective.
  for (int tile = 0; tile <= 28; ++tile) {
    asm volatile("s_waitcnt vmcnt(12)\ns_barrier" ::: "memory");
    COMPUTE(buf);
    asm volatile("s_barrier" ::: "memory");  // all waves done reading buf
    STAGE(tile + 3, buf);
    buf = (buf == 2) ? 0 : buf + 1;
  }
  // tail: tiles 29 (12 outstanding after wait), 30 (6), 31 (0)
  asm volatile("s_waitcnt vmcnt(12)\ns_barrier" ::: "memory");
  COMPUTE(buf);
  buf = (buf == 2) ? 0 : buf + 1;
  asm volatile("s_waitcnt vmcnt(6)\ns_barrier" ::: "memory");
  COMPUTE(buf);
  buf = (buf == 2) ? 0 : buf + 1;
  asm volatile("s_waitcnt vmcnt(0)\ns_barrier" ::: "memory");
  COMPUTE(buf);

  // epilogue: C/D layout col=lane&15, row=quad*4+reg (verified)
#pragma unroll
  for (int ni = 0; ni < 4; ++ni) {
    const int gn = n0 + wn + ni * 16 + l15;
    const float bv = Bias[gn];
#pragma unroll
    for (int mi = 0; mi < 4; ++mi) {
      const int gm = m0 + wm + mi * 16 + quad * 4;
#pragma unroll
      for (int r = 0; r < 4; ++r)
        Out[(size_t)(gm + r) * OD + gn] = acc[mi][ni][r] + bv;
    }
  }
}

// ---------------------------------------------------------------------------
// Fallback (ws too small): round-2 fused kernel, known-correct.
// ---------------------------------------------------------------------------
__global__ __launch_bounds__(256) void gemm_fused(const float* __restrict__ X,
                                                  const float* __restrict__ W,
                                                  const float* __restrict__ Bias,
                                                  const int* __restrict__ idx,
                                                  float* __restrict__ Out) {
  __shared__ ushort lA[128 * 32];
  __shared__ ushort lB[32 * 128];
  const int t    = threadIdx.x;
  const int m0   = blockIdx.y * 128;
  const int n0   = blockIdx.x * 128;
  const int wave = t >> 6;
  const int lane = t & 63;
  const int wm   = (wave & 1) * 64;
  const int wn   = (wave >> 1) * 64;
  const int l15  = lane & 15;
  const int quad = lane >> 4;

  f32x4 acc[4][4];
#pragma unroll
  for (int i = 0; i < 4; ++i)
#pragma unroll
    for (int j = 0; j < 4; ++j) acc[i][j] = (f32x4){0.f, 0.f, 0.f, 0.f};

  for (int kt = 0; kt < KD / 32; ++kt) {
    const int k0 = kt * 32;
    if (k0 < FD) {
#pragma unroll
      for (int r = 0; r < 2; ++r) {
        const int q = r * 256 + t;
        const int row = q >> 2, ch = q & 3;
        *reinterpret_cast<bf16x8*>(lA + q * 8) =
            cvt8(X + (size_t)(m0 + row) * FD + k0 + ch * 8);
      }
    } else {
      const int kc = k0 - FD;
#pragma unroll
      for (int r = 0; r < 2; ++r) {
        const int q = r * 256 + t;
        const int row = q >> 2, ch = q & 3;
        float a8[8] = {0.f, 0.f, 0.f, 0.f, 0.f, 0.f, 0.f, 0.f};
        const int* ip = idx + (size_t)(m0 + row) * NB;
#pragma unroll
        for (int j = 0; j < NB; ++j) {
          const float* p = X + (size_t)ip[j] * FD + kc + ch * 8;
          const float4 a = *(const float4*)p;
          const float4 b = *(const float4*)(p + 4);
          a8[0] += a.x; a8[1] += a.y; a8[2] += a.z; a8[3] += a.w;
          a8[4] += b.x; a8[5] += b.y; a8[6] += b.z; a8[7] += b.w;
        }
        bf16x8 v;
#pragma unroll
        for (int e = 0; e < 8; ++e) v[e] = (short)f2bf(a8[e] * 0.1f);
        *reinterpret_cast<bf16x8*>(lA + q * 8) = v;
      }
    }
#pragma unroll
    for (int r = 0; r < 2; ++r) {
      const int q = r * 256 + t;
      const int kr = q >> 4, ch = q & 15;
      *reinterpret_cast<bf16x8*>(lB + q * 8) =
          cvt8(W + (size_t)(k0 + kr) * OD + n0 + ch * 8);
    }
    __syncthreads();

    bf16x8 afr[4], bfr[4];
#pragma unroll
    for (int mi = 0; mi < 4; ++mi)
      afr[mi] = *reinterpret_cast<const bf16x8*>(lA + (wm + mi * 16 + l15) * 32 + quad * 8);
#pragma unroll
    for (int ni = 0; ni < 4; ++ni) {
      const int col = wn + ni * 16 + l15;
#pragma unroll
      for (int j = 0; j < 8; ++j)
        bfr[ni][j] = (short)lB[(quad * 8 + j) * 128 + col];
    }
#pragma unroll
    for (int mi = 0; mi < 4; ++mi)
#pragma unroll
      for (int ni = 0; ni < 4; ++ni)
        acc[mi][ni] = __builtin_amdgcn_mfma_f32_16x16x32_bf16(afr[mi], bfr[ni], acc[mi][ni], 0, 0, 0);
    __syncthreads();
  }
#pragma unroll
  for (int ni = 0; ni < 4; ++ni) {
    const int gn = n0 + wn + ni * 16 + l15;
    const float bv = Bias[gn];
#pragma unroll
    for (int mi = 0; mi < 4; ++mi) {
      const int gm = m0 + wm + mi * 16 + quad * 4;
#pragma unroll
      for (int r = 0; r < 4; ++r)
        Out[(size_t)(gm + r) * OD + gn] = acc[mi][ni][r] + bv;
    }
  }
}

extern "C" void kernel_launch(void* const* d_in, const int* in_sizes, int n_in,
                              void* d_out, int out_size, void* d_ws, size_t ws_size,
                              hipStream_t stream) {
  const float* X   = (const float*)d_in[0];
  // d_in[1] = A: dead code in the reference
  const float* W   = (const float*)d_in[2];
  const float* b   = (const float*)d_in[3];
  const int*   idx = (const int*)d_in[4];
  float* out = (float*)d_out;

  const size_t need = ((size_t)NN * KD + (size_t)OD * KD) * sizeof(ushort);  // 36 MB
  if (ws_size >= need) {
    ushort* Ab  = (ushort*)d_ws;                 // [8192][2048] bf16, 32 MB
    ushort* Wtb = Ab + (size_t)NN * KD;          // [1024][2048] bf16, 4 MB

    xconv<<<NN * FD / (256 * 8), 256, 0, stream>>>(X, Ab);
    wconv<<<dim3(KD / 64, OD / 64), dim3(64, 16), 0, stream>>>(W, Wtb);
    aggk<<<NN / 2, 256, 0, stream>>>(idx, Ab);
    gemm_256x128<<<256, 512, 0, stream>>>(Ab, Wtb, b, out);
  } else {
    gemm_fused<<<dim3(OD / 128, NN / 128), 256, 0, stream>>>(X, W, b, idx, out);
  }
}

// Round 3
// 388.359 us; speedup vs baseline: 1.1609x; 1.0220x over previous
//
#include <hip/hip_runtime.h>
#include <stdint.h>

// SageLayer: N=8192, F=1024, O=1024, K=2F=2048, NUM_NEIGH=10. Inputs f32.
//
// Round 3: true fine-phased GEMM schedule (m201-style) at 256x128.
// Round-2's coarse 3-deep pipeline was null (m196: coarse split without the
// per-phase ds_read||stage||MFMA interleave doesn't pay). This version:
// per K-tile, 2 phases; each phase = {8 ds_read_b128 (one k-substep's
// fragments) || issue half of tile+2's global_load_lds} -> s_barrier ->
// setprio(1) + 16 MFMA + setprio(0) -> s_barrier. Tile-trailing counted
// s_waitcnt vmcnt(6) + s_barrier (next tile's 6 loads stay in flight; never
// drains to 0 until the peeled tail 6->0). 3 LDS buffers (144 KB), 8 waves,
// 1 block/CU. Swizzle, fragment map, epilogue, accumulation order identical
// to the verified round-0 kernel (bit-identical output).
#define NN 8192
#define FD 1024
#define OD 1024
#define KD 2048
#define NB 10

typedef short bf16x8 __attribute__((ext_vector_type(8)));
typedef float f32x4  __attribute__((ext_vector_type(4)));

static __device__ __forceinline__ float bf2f(ushort u) {
  union { uint32_t i; float f; } v; v.i = ((uint32_t)u) << 16; return v.f;
}
static __device__ __forceinline__ ushort f2bf(float f) {
  union { float f; uint32_t i; } v; v.f = f;
  uint32_t x = v.i;
  return (ushort)((x + 0x7FFFu + ((x >> 16) & 1u)) >> 16);  // RNE
}
static __device__ __forceinline__ bf16x8 cvt8(const float* p) {
  const float4 a = *reinterpret_cast<const float4*>(p);
  const float4 b = *reinterpret_cast<const float4*>(p + 4);
  bf16x8 v;
  v[0] = (short)f2bf(a.x); v[1] = (short)f2bf(a.y);
  v[2] = (short)f2bf(a.z); v[3] = (short)f2bf(a.w);
  v[4] = (short)f2bf(b.x); v[5] = (short)f2bf(b.y);
  v[6] = (short)f2bf(b.z); v[7] = (short)f2bf(b.w);
  return v;
}

// async global->LDS, 16 B/lane. LDS dest must be wave-uniform base + lane*16.
static __device__ __forceinline__ void async16(const ushort* g, ushort* l) {
  __builtin_amdgcn_global_load_lds(
      (const __attribute__((address_space(1))) uint32_t*)(const void*)g,
      (__attribute__((address_space(3))) uint32_t*)(void*)l, 16, 0, 0);
}

// ---------------------------------------------------------------------------
// xconv: Ab[i][0:1024] = bf16(X[i][:]).  Ab row stride = KD (2048).
// ---------------------------------------------------------------------------
__global__ __launch_bounds__(256) void xconv(const float* __restrict__ X,
                                             ushort* __restrict__ Ab) {
  const int q   = blockIdx.x * 256 + threadIdx.x;
  const int row = q >> 7;
  const int col = (q & 127) * 8;
  const bf16x8 v = cvt8(X + (size_t)row * FD + col);
  *reinterpret_cast<bf16x8*>(Ab + (size_t)row * KD + col) = v;
}

// ---------------------------------------------------------------------------
// aggk: Ab[i][1024:2048] = bf16(mean_j Xb[idx[i][j]][:]), gathering bf16 rows
// from Ab's left half. 2 rows per 256-thread block.
// ---------------------------------------------------------------------------
__global__ __launch_bounds__(256) void aggk(const int* __restrict__ idx,
                                            ushort* __restrict__ Ab) {
  const int row  = blockIdx.x * 2 + (threadIdx.x >> 7);
  const int lane = threadIdx.x & 127;
  const int col  = lane * 8;
  const int* ip = idx + (size_t)row * NB;
  int nb[NB];
#pragma unroll
  for (int j = 0; j < NB; ++j) nb[j] = ip[j];
  float acc[8] = {0.f, 0.f, 0.f, 0.f, 0.f, 0.f, 0.f, 0.f};
#pragma unroll
  for (int j = 0; j < NB; ++j) {
    const uint4 v = *reinterpret_cast<const uint4*>(Ab + (size_t)nb[j] * KD + col);
    const ushort* u = reinterpret_cast<const ushort*>(&v);
#pragma unroll
    for (int e = 0; e < 8; ++e) acc[e] += bf2f(u[e]);
  }
  bf16x8 o;
#pragma unroll
  for (int e = 0; e < 8; ++e) o[e] = (short)f2bf(acc[e] * 0.1f);
  *reinterpret_cast<bf16x8*>(Ab + (size_t)row * KD + FD + col) = o;
}

// ---------------------------------------------------------------------------
// wconv: Wtb[n][k] = bf16(W[k][n]).  64x64 LDS-tiled transpose + convert.
// ---------------------------------------------------------------------------
__global__ __launch_bounds__(1024) void wconv(const float* __restrict__ W,
                                              ushort* __restrict__ Wtb) {
  __shared__ float tile[64][65];
  const int k0 = blockIdx.x * 64;
  const int n0 = blockIdx.y * 64;
  const int tx = threadIdx.x;
  const int ty = threadIdx.y;
#pragma unroll
  for (int r = 0; r < 4; ++r) {
    const int kl = ty + r * 16;
    tile[kl][tx] = W[(size_t)(k0 + kl) * OD + n0 + tx];
  }
  __syncthreads();
#pragma unroll
  for (int r = 0; r < 4; ++r) {
    const int nl = ty + r * 16;
    Wtb[(size_t)(n0 + nl) * KD + k0 + tx] = f2bf(tile[tx][nl]);
  }
}

// ---------------------------------------------------------------------------
// gemm_8ph: Out = Ab @ Wtb^T + b.  See header comment.
// Tile 256x128, BK=64, 512 thr = 8 waves (4Mx2N, wave tile 64x64).
// ---------------------------------------------------------------------------
__global__ __launch_bounds__(512, 2) void gemm_8ph(const ushort* __restrict__ Ab,
                                                   const ushort* __restrict__ Wtb,
                                                   const float* __restrict__ Bias,
                                                   float* __restrict__ Out) {
  __shared__ ushort lA[3 * 256 * 64];  // 96 KB
  __shared__ ushort lB[3 * 128 * 64];  // 48 KB
  const int t  = threadIdx.x;
  const int id  = blockIdx.x;          // 0..255
  const int xcd = id & 7;
  const int j   = id >> 3;             // 0..31
  const int m0  = (xcd * 4 + (j >> 3)) * 256;
  const int n0  = (j & 7) * 128;

  const int wave = t >> 6;             // 0..7
  const int lane = t & 63;
  const int wm   = (wave >> 1) * 64;   // 0,64,128,192
  const int wn   = (wave & 1) * 64;    // 0,64
  const int l15  = lane & 15;
  const int quad = lane >> 4;

  f32x4 acc[4][4];
#pragma unroll
  for (int i = 0; i < 4; ++i)
#pragma unroll
    for (int jj = 0; jj < 4; ++jj) acc[i][jj] = (f32x4){0.f, 0.f, 0.f, 0.f};

  // staging coords: slot q holds global chunk c=(ch-row)&7 so that the
  // swizzled slot offset equals the lane-contiguous q*8.
  const ushort* gA[4];
  const ushort* gB[2];
#pragma unroll
  for (int i = 0; i < 4; ++i) {
    const int q   = i * 512 + t;       // 0..2047
    const int row = q >> 3;            // 0..255
    const int c   = ((q & 7) - row) & 7;
    gA[i] = Ab + (size_t)(m0 + row) * KD + c * 8;
  }
#pragma unroll
  for (int i = 0; i < 2; ++i) {
    const int q   = i * 512 + t;       // 0..1023
    const int row = q >> 3;            // 0..127
    const int c   = ((q & 7) - row) & 7;
    gB[i] = Wtb + (size_t)(n0 + row) * KD + c * 8;
  }

  // per-thread constant LDS fragment offsets (ushort units)
  int offA[2][4], offB[2][4];
#pragma unroll
  for (int s = 0; s < 2; ++s) {
    const int c = s * 4 + quad;
#pragma unroll
    for (int mi = 0; mi < 4; ++mi) {
      const int r = wm + mi * 16 + l15;
      offA[s][mi] = r * 64 + ((c + r) & 7) * 8;
    }
#pragma unroll
    for (int ni = 0; ni < 4; ++ni) {
      const int r = wn + ni * 16 + l15;
      offB[s][ni] = r * 64 + ((c + r) & 7) * 8;
    }
  }

  // prologue: stage tiles 0,1 (12 loads in flight), then make tile 0 visible
  {
    ushort* la0 = lA;            ushort* lb0 = lB;
    ushort* la1 = lA + 256 * 64; ushort* lb1 = lB + 128 * 64;
#pragma unroll
    for (int i = 0; i < 4; ++i) async16(gA[i], la0 + (i * 512 + t) * 8);
#pragma unroll
    for (int i = 0; i < 2; ++i) async16(gB[i], lb0 + (i * 512 + t) * 8);
#pragma unroll
    for (int i = 0; i < 4; ++i) async16(gA[i] + 64, la1 + (i * 512 + t) * 8);
#pragma unroll
    for (int i = 0; i < 2; ++i) async16(gB[i] + 64, lb1 + (i * 512 + t) * 8);
  }
  asm volatile("s_waitcnt vmcnt(6)\ns_barrier" ::: "memory");

  int cur = 0, nx2 = 2;
  for (int tile = 0; tile < 32; ++tile) {
    const ushort* la = lA + cur * (256 * 64);
    const ushort* lb = lB + cur * (128 * 64);
    ushort* sa = lA + nx2 * (256 * 64);
    ushort* sb = lB + nx2 * (128 * 64);
    const bool st = tile < 30;
    const int k2 = (tile + 2) * 64;

    // ---- phase 0: k-substep 0 fragments || stage A(tile+2) ----
    {
      bf16x8 afr[4], bfr[4];
#pragma unroll
      for (int mi = 0; mi < 4; ++mi)
        afr[mi] = *reinterpret_cast<const bf16x8*>(la + offA[0][mi]);
#pragma unroll
      for (int ni = 0; ni < 4; ++ni)
        bfr[ni] = *reinterpret_cast<const bf16x8*>(lb + offB[0][ni]);
      if (st) {
#pragma unroll
        for (int i = 0; i < 4; ++i) async16(gA[i] + k2, sa + (i * 512 + t) * 8);
      }
      asm volatile("s_barrier" ::: "memory");
      __builtin_amdgcn_s_setprio(1);
#pragma unroll
      for (int mi = 0; mi < 4; ++mi)
#pragma unroll
        for (int ni = 0; ni < 4; ++ni)
          acc[mi][ni] = __builtin_amdgcn_mfma_f32_16x16x32_bf16(afr[mi], bfr[ni], acc[mi][ni], 0, 0, 0);
      __builtin_amdgcn_s_setprio(0);
      asm volatile("s_barrier" ::: "memory");
    }
    // ---- phase 1: k-substep 1 fragments || stage B(tile+2) ----
    {
      bf16x8 afr[4], bfr[4];
#pragma unroll
      for (int mi = 0; mi < 4; ++mi)
        afr[mi] = *reinterpret_cast<const bf16x8*>(la + offA[1][mi]);
#pragma unroll
      for (int ni = 0; ni < 4; ++ni)
        bfr[ni] = *reinterpret_cast<const bf16x8*>(lb + offB[1][ni]);
      if (st) {
#pragma unroll
        for (int i = 0; i < 2; ++i) async16(gB[i] + k2, sb + (i * 512 + t) * 8);
      }
      asm volatile("s_barrier" ::: "memory");
      __builtin_amdgcn_s_setprio(1);
#pragma unroll
      for (int mi = 0; mi < 4; ++mi)
#pragma unroll
        for (int ni = 0; ni < 4; ++ni)
          acc[mi][ni] = __builtin_amdgcn_mfma_f32_16x16x32_bf16(afr[mi], bfr[ni], acc[mi][ni], 0, 0, 0);
      __builtin_amdgcn_s_setprio(0);
      asm volatile("s_barrier" ::: "memory");
    }
    // ---- tile boundary: make tile+1 visible; keep tile+2 in flight ----
    if (tile < 30) {
      asm volatile("s_waitcnt vmcnt(6)\ns_barrier" ::: "memory");
    } else if (tile == 30) {
      asm volatile("s_waitcnt vmcnt(0)\ns_barrier" ::: "memory");
    }
    cur = (cur == 2) ? 0 : cur + 1;
    nx2 = (nx2 == 2) ? 0 : nx2 + 1;
  }

  // epilogue: C/D layout col=lane&15, row=quad*4+reg (verified)
#pragma unroll
  for (int ni = 0; ni < 4; ++ni) {
    const int gn = n0 + wn + ni * 16 + l15;
    const float bv = Bias[gn];
#pragma unroll
    for (int mi = 0; mi < 4; ++mi) {
      const int gm = m0 + wm + mi * 16 + quad * 4;
#pragma unroll
      for (int r = 0; r < 4; ++r)
        Out[(size_t)(gm + r) * OD + gn] = acc[mi][ni][r] + bv;
    }
  }
}

// ---------------------------------------------------------------------------
// Fallback (ws too small): known-correct fused kernel.
// ---------------------------------------------------------------------------
__global__ __launch_bounds__(256) void gemm_fused(const float* __restrict__ X,
                                                  const float* __restrict__ W,
                                                  const float* __restrict__ Bias,
                                                  const int* __restrict__ idx,
                                                  float* __restrict__ Out) {
  __shared__ ushort lA[128 * 32];
  __shared__ ushort lB[32 * 128];
  const int t    = threadIdx.x;
  const int m0   = blockIdx.y * 128;
  const int n0   = blockIdx.x * 128;
  const int wave = t >> 6;
  const int lane = t & 63;
  const int wm   = (wave & 1) * 64;
  const int wn   = (wave >> 1) * 64;
  const int l15  = lane & 15;
  const int quad = lane >> 4;

  f32x4 acc[4][4];
#pragma unroll
  for (int i = 0; i < 4; ++i)
#pragma unroll
    for (int j = 0; j < 4; ++j) acc[i][j] = (f32x4){0.f, 0.f, 0.f, 0.f};

  for (int kt = 0; kt < KD / 32; ++kt) {
    const int k0 = kt * 32;
    if (k0 < FD) {
#pragma unroll
      for (int r = 0; r < 2; ++r) {
        const int q = r * 256 + t;
        const int row = q >> 2, ch = q & 3;
        *reinterpret_cast<bf16x8*>(lA + q * 8) =
            cvt8(X + (size_t)(m0 + row) * FD + k0 + ch * 8);
      }
    } else {
      const int kc = k0 - FD;
#pragma unroll
      for (int r = 0; r < 2; ++r) {
        const int q = r * 256 + t;
        const int row = q >> 2, ch = q & 3;
        float a8[8] = {0.f, 0.f, 0.f, 0.f, 0.f, 0.f, 0.f, 0.f};
        const int* ip = idx + (size_t)(m0 + row) * NB;
#pragma unroll
        for (int j = 0; j < NB; ++j) {
          const float* p = X + (size_t)ip[j] * FD + kc + ch * 8;
          const float4 a = *(const float4*)p;
          const float4 b = *(const float4*)(p + 4);
          a8[0] += a.x; a8[1] += a.y; a8[2] += a.z; a8[3] += a.w;
          a8[4] += b.x; a8[5] += b.y; a8[6] += b.z; a8[7] += b.w;
        }
        bf16x8 v;
#pragma unroll
        for (int e = 0; e < 8; ++e) v[e] = (short)f2bf(a8[e] * 0.1f);
        *reinterpret_cast<bf16x8*>(lA + q * 8) = v;
      }
    }
#pragma unroll
    for (int r = 0; r < 2; ++r) {
      const int q = r * 256 + t;
      const int kr = q >> 4, ch = q & 15;
      *reinterpret_cast<bf16x8*>(lB + q * 8) =
          cvt8(W + (size_t)(k0 + kr) * OD + n0 + ch * 8);
    }
    __syncthreads();

    bf16x8 afr[4], bfr[4];
#pragma unroll
    for (int mi = 0; mi < 4; ++mi)
      afr[mi] = *reinterpret_cast<const bf16x8*>(lA + (wm + mi * 16 + l15) * 32 + quad * 8);
#pragma unroll
    for (int ni = 0; ni < 4; ++ni) {
      const int col = wn + ni * 16 + l15;
#pragma unroll
      for (int j = 0; j < 8; ++j)
        bfr[ni][j] = (short)lB[(quad * 8 + j) * 128 + col];
    }
#pragma unroll
    for (int mi = 0; mi < 4; ++mi)
#pragma unroll
      for (int ni = 0; ni < 4; ++ni)
        acc[mi][ni] = __builtin_amdgcn_mfma_f32_16x16x32_bf16(afr[mi], bfr[ni], acc[mi][ni], 0, 0, 0);
    __syncthreads();
  }
#pragma unroll
  for (int ni = 0; ni < 4; ++ni) {
    const int gn = n0 + wn + ni * 16 + l15;
    const float bv = Bias[gn];
#pragma unroll
    for (int mi = 0; mi < 4; ++mi) {
      const int gm = m0 + wm + mi * 16 + quad * 4;
#pragma unroll
      for (int r = 0; r < 4; ++r)
        Out[(size_t)(gm + r) * OD + gn] = acc[mi][ni][r] + bv;
    }
  }
}

extern "C" void kernel_launch(void* const* d_in, const int* in_sizes, int n_in,
                              void* d_out, int out_size, void* d_ws, size_t ws_size,
                              hipStream_t stream) {
  const float* X   = (const float*)d_in[0];
  // d_in[1] = A: dead code in the reference
  const float* W   = (const float*)d_in[2];
  const float* b   = (const float*)d_in[3];
  const int*   idx = (const int*)d_in[4];
  float* out = (float*)d_out;

  const size_t need = ((size_t)NN * KD + (size_t)OD * KD) * sizeof(ushort);  // 36 MB
  if (ws_size >= need) {
    ushort* Ab  = (ushort*)d_ws;                 // [8192][2048] bf16, 32 MB
    ushort* Wtb = Ab + (size_t)NN * KD;          // [1024][2048] bf16, 4 MB

    xconv<<<NN * FD / (256 * 8), 256, 0, stream>>>(X, Ab);
    wconv<<<dim3(KD / 64, OD / 64), dim3(64, 16), 0, stream>>>(W, Wtb);
    aggk<<<NN / 2, 256, 0, stream>>>(idx, Ab);
    gemm_8ph<<<256, 512, 0, stream>>>(Ab, Wtb, b, out);
  } else {
    gemm_fused<<<dim3(OD / 128, NN / 128), 256, 0, stream>>>(X, W, b, idx, out);
  }
}